// Round 4
// baseline (320.155 us; speedup 1.0000x reference)
//
#include <hip/hip_runtime.h>
#include <math.h>

#define BATCH 2
#define SEQ   2048
#define EMB   1024
#define HEADS 16
#define N3E   3072
#define MROWS (BATCH*SEQ)     // 4096

typedef __attribute__((ext_vector_type(8))) short  bf16x8;
typedef __attribute__((ext_vector_type(4))) float  f32x4;

__device__ __forceinline__ ushort f2bu(float f) {
    // fp32 -> bf16 bits, round-to-nearest-even (inputs are finite; no NaN path)
    union { float f; unsigned u; } x; x.f = f;
    unsigned r = x.u + 0x7FFFu + ((x.u >> 16) & 1u);
    return (ushort)(r >> 16);
}

// ---------------------------------------------------------------------------
// float -> bf16 cast, 4 elements/thread
// ---------------------------------------------------------------------------
__global__ void cast_bf16(const float* __restrict__ in, ushort* __restrict__ out, int n4) {
    int i = blockIdx.x * blockDim.x + threadIdx.x;
    if (i < n4) {
        float4 v = ((const float4*)in)[i];
        ushort4 o;
        o.x = f2bu(v.x); o.y = f2bu(v.y); o.z = f2bu(v.z); o.w = f2bu(v.w);
        ((ushort4*)out)[i] = o;
    }
}

// ---------------------------------------------------------------------------
// W[K][N] fp32 -> Wt[N][K] bf16 (32x32 tiles via LDS)
// ---------------------------------------------------------------------------
__global__ void transpose_cast(const float* __restrict__ W, ushort* __restrict__ Wt,
                               int K, int N) {
    __shared__ float t[32][33];
    const int bn = blockIdx.x * 32, bk = blockIdx.y * 32;
    const int tx = threadIdx.x, ty = threadIdx.y;   // (32, 8)
    #pragma unroll
    for (int j = 0; j < 4; ++j)
        t[ty + j * 8][tx] = W[(size_t)(bk + ty + j * 8) * N + bn + tx];
    __syncthreads();
    #pragma unroll
    for (int j = 0; j < 4; ++j)
        Wt[(size_t)(bn + ty + j * 8) * K + bk + tx] = f2bu(t[tx][ty + j * 8]);
}

// ---------------------------------------------------------------------------
// MFMA GEMM: C[M][N] = A[M][K](bf16) * Bt[N][K]^T(bf16) + bias, out fp32 or bf16.
// 128x128 tile, BK=32, 4 waves (2x2), each wave 64x64 = 4x4 fragments 16x16x32.
// ---------------------------------------------------------------------------
template<bool OUT_BF16>
__global__ __launch_bounds__(256) void gemm_bt(const ushort* __restrict__ A,
                                               const ushort* __restrict__ Bt,
                                               const float* __restrict__ bias,
                                               void* __restrict__ Cout,
                                               int M, int N, int K)
{
    __shared__ ushort As[128][40];   // rows 80B (16B-mult), 2-way read conflicts
    __shared__ ushort Bs[128][40];

    const int tid  = threadIdx.x;
    const int lane = tid & 63, w = tid >> 6;
    const int wr = w >> 1, wc = w & 1;
    const int l15 = lane & 15, l4 = lane >> 4;
    const int m0 = blockIdx.y * 128, n0 = blockIdx.x * 128;

    const f32x4 fzero = {0.f, 0.f, 0.f, 0.f};
    f32x4 acc[4][4];
    #pragma unroll
    for (int m = 0; m < 4; ++m)
        #pragma unroll
        for (int n = 0; n < 4; ++n) acc[m][n] = fzero;

    for (int k0 = 0; k0 < K; k0 += 32) {
        #pragma unroll
        for (int r = 0; r < 2; ++r) {
            const int i2 = tid + r * 256;         // 512 x 16B covers both tiles' halves
            const int row = i2 >> 2, seg = i2 & 3;
            *(bf16x8*)&As[row][seg * 8] =
                *(const bf16x8*)&A[(size_t)(m0 + row) * K + k0 + seg * 8];
            *(bf16x8*)&Bs[row][seg * 8] =
                *(const bf16x8*)&Bt[(size_t)(n0 + row) * K + k0 + seg * 8];
        }
        __syncthreads();

        bf16x8 am[4], bn[4];
        #pragma unroll
        for (int m = 0; m < 4; ++m) am[m] = *(bf16x8*)&As[wr * 64 + m * 16 + l15][l4 * 8];
        #pragma unroll
        for (int n = 0; n < 4; ++n) bn[n] = *(bf16x8*)&Bs[wc * 64 + n * 16 + l15][l4 * 8];
        #pragma unroll
        for (int m = 0; m < 4; ++m)
            #pragma unroll
            for (int n = 0; n < 4; ++n)
                acc[m][n] = __builtin_amdgcn_mfma_f32_16x16x32_bf16(am[m], bn[n], acc[m][n], 0, 0, 0);
        __syncthreads();
    }

    // Epilogue. C/D layout (HW-verified): row=(lane>>4)*4+reg, col=lane&15.
    #pragma unroll
    for (int m = 0; m < 4; ++m)
        #pragma unroll
        for (int n = 0; n < 4; ++n)
            #pragma unroll
            for (int r = 0; r < 4; ++r) {
                const int row = m0 + wr * 64 + m * 16 + l4 * 4 + r;
                const int col = n0 + wc * 64 + n * 16 + l15;
                const float v = acc[m][n][r] + bias[col];
                if (OUT_BF16) ((ushort*)Cout)[(size_t)row * N + col] = f2bu(v);
                else          ((float*)Cout)[(size_t)row * N + col]  = v;
            }
}

// ---------------------------------------------------------------------------
// Flash attention, bf16 MFMA. Block = (qtile 64, h, b), 4 waves; wave w owns
// q rows qt*64 + w*16 .. +15. KV tiles of 64. Online softmax in fp32.
// qkv view (reference reshape): q[b,h,l,d] = qkvb[b*2048 + h*128 + (l>>4)]
//                                               [(l&15)*192 + {0|64|128} + d]
// ---------------------------------------------------------------------------
__global__ __launch_bounds__(256) void mha_mfma(const ushort* __restrict__ qkv,
                                                ushort* __restrict__ att)
{
    __shared__ ushort Ks[64][72];      // [kv][d]   rows 144B
    __shared__ ushort Vt[64][72];      // [d][kv]
    __shared__ ushort Ps[4][16][72];   // per-wave P [q][kv]

    const int tid  = threadIdx.x;
    const int lane = tid & 63, w = tid >> 6;
    const int l15 = lane & 15, l4 = lane >> 4;
    const int qt = blockIdx.x, h = blockIdx.y, b = blockIdx.z;
    const size_t rowbase = (size_t)b * SEQ + (size_t)h * 128;

    // Q fragments (held in registers for all 32 KV tiles)
    bf16x8 aq[2];
    {
        const int lq = qt * 64 + w * 16 + l15;
        const size_t base = (rowbase + (lq >> 4)) * N3E + (size_t)(lq & 15) * 192;
        aq[0] = *(const bf16x8*)&qkv[base +      l4 * 8];
        aq[1] = *(const bf16x8*)&qkv[base + 32 + l4 * 8];
    }

    const f32x4 fzero = {0.f, 0.f, 0.f, 0.f};
    float m_run[4] = {-INFINITY, -INFINITY, -INFINITY, -INFINITY};
    float l_run[4] = {0.f, 0.f, 0.f, 0.f};
    f32x4 o[4];
    #pragma unroll
    for (int f = 0; f < 4; ++f) o[f] = fzero;

    for (int jt = 0; jt < 32; ++jt) {
        __syncthreads();   // Ks/Vt/Ps free (prev PV done)

        // Stage K row-major, V transposed.
        #pragma unroll
        for (int r = 0; r < 2; ++r) {
            const int i2 = tid + r * 256;
            const int krow = i2 >> 3, seg = i2 & 7;
            const int kv = jt * 64 + krow;
            const size_t gb = (rowbase + (kv >> 4)) * N3E + (size_t)(kv & 15) * 192;
            *(bf16x8*)&Ks[krow][seg * 8] = *(const bf16x8*)&qkv[gb + 64 + seg * 8];
            const bf16x8 v8 = *(const bf16x8*)&qkv[gb + 128 + seg * 8];
            #pragma unroll
            for (int j = 0; j < 8; ++j) Vt[seg * 8 + j][krow] = (ushort)v8[j];
        }
        __syncthreads();

        // S = Q K^T (A=Q rows, B-frag = K rows read as columns of K^T)
        f32x4 s4[4];
        #pragma unroll
        for (int f = 0; f < 4; ++f) s4[f] = fzero;
        #pragma unroll
        for (int s = 0; s < 2; ++s)
            #pragma unroll
            for (int f = 0; f < 4; ++f) {
                const bf16x8 kb = *(bf16x8*)&Ks[f * 16 + l15][s * 32 + l4 * 8];
                s4[f] = __builtin_amdgcn_mfma_f32_16x16x32_bf16(aq[s], kb, s4[f], 0, 0, 0);
            }
        #pragma unroll
        for (int f = 0; f < 4; ++f) s4[f] *= 0.125f;   // 1/sqrt(64), before max

        // Online softmax. Lane holds rows (l4*4+r), cols f*16+l15.
        #pragma unroll
        for (int r = 0; r < 4; ++r) {
            float rm = fmaxf(fmaxf(s4[0][r], s4[1][r]), fmaxf(s4[2][r], s4[3][r]));
            rm = fmaxf(rm, __shfl_xor(rm, 1, 16));
            rm = fmaxf(rm, __shfl_xor(rm, 2, 16));
            rm = fmaxf(rm, __shfl_xor(rm, 4, 16));
            rm = fmaxf(rm, __shfl_xor(rm, 8, 16));
            const float mn   = fmaxf(m_run[r], rm);
            const float corr = __expf(m_run[r] - mn);   // 0 on first tile
            float p0 = __expf(s4[0][r] - mn);
            float p1 = __expf(s4[1][r] - mn);
            float p2 = __expf(s4[2][r] - mn);
            float p3 = __expf(s4[3][r] - mn);
            float rs = p0 + p1 + p2 + p3;
            rs += __shfl_xor(rs, 1, 16);
            rs += __shfl_xor(rs, 2, 16);
            rs += __shfl_xor(rs, 4, 16);
            rs += __shfl_xor(rs, 8, 16);
            l_run[r] = l_run[r] * corr + rs;
            m_run[r] = mn;
            #pragma unroll
            for (int f = 0; f < 4; ++f) o[f][r] *= corr;
            const int qrow = l4 * 4 + r;
            Ps[w][qrow][0 * 16 + l15] = f2bu(p0);
            Ps[w][qrow][1 * 16 + l15] = f2bu(p1);
            Ps[w][qrow][2 * 16 + l15] = f2bu(p2);
            Ps[w][qrow][3 * 16 + l15] = f2bu(p3);
        }
        __syncthreads();   // Ps complete (also orders LDS within wave)

        // O += P V  (A=P rows q=l&15; B-frag = Vt rows = V columns)
        #pragma unroll
        for (int s = 0; s < 2; ++s) {
            const bf16x8 pa = *(bf16x8*)&Ps[w][l15][s * 32 + l4 * 8];
            #pragma unroll
            for (int f = 0; f < 4; ++f) {
                const bf16x8 vb = *(bf16x8*)&Vt[f * 16 + l15][s * 32 + l4 * 8];
                o[f] = __builtin_amdgcn_mfma_f32_16x16x32_bf16(pa, vb, o[f], 0, 0, 0);
            }
        }
    }

    // Epilogue: normalize, write att[b*2048+l][h*64+d] as bf16.
    #pragma unroll
    for (int r = 0; r < 4; ++r) {
        const float inv = 1.f / l_run[r];
        const int lq = qt * 64 + w * 16 + l4 * 4 + r;
        const size_t orow = ((size_t)b * SEQ + lq) * EMB + h * 64;
        #pragma unroll
        for (int f = 0; f < 4; ++f)
            att[orow + f * 16 + l15] = f2bu(o[f][r] * inv);
    }
}

// ---------------------------------------------------------------------------
extern "C" void kernel_launch(void* const* d_in, const int* in_sizes, int n_in,
                              void* d_out, int out_size, void* d_ws, size_t ws_size,
                              hipStream_t stream)
{
    const float* x     = (const float*)d_in[0];
    const float* W_qkv = (const float*)d_in[1];
    const float* b_qkv = (const float*)d_in[2];
    const float* W_out = (const float*)d_in[3];
    const float* b_out = (const float*)d_in[4];

    ushort* xb   = (ushort*)d_ws;                        // 4096x1024  (8 MB)
    ushort* wqt  = xb   + (size_t)MROWS * EMB;           // 3072x1024  (6 MB)
    ushort* wot  = wqt  + (size_t)N3E * EMB;             // 1024x1024  (2 MB)
    ushort* qkvb = wot  + (size_t)EMB * EMB;             // 4096x3072  (24 MB)
    ushort* attb = qkvb + (size_t)MROWS * N3E;           // 4096x1024  (8 MB)

    cast_bf16<<<(MROWS * EMB / 4 + 255) / 256, 256, 0, stream>>>(x, xb, MROWS * EMB / 4);
    transpose_cast<<<dim3(N3E / 32, EMB / 32), dim3(32, 8), 0, stream>>>(W_qkv, wqt, EMB, N3E);
    transpose_cast<<<dim3(EMB / 32, EMB / 32), dim3(32, 8), 0, stream>>>(W_out, wot, EMB, EMB);

    gemm_bt<true><<<dim3(N3E / 128, MROWS / 128), 256, 0, stream>>>(
        xb, wqt, b_qkv, qkvb, MROWS, N3E, EMB);

    mha_mfma<<<dim3(SEQ / 64, HEADS, BATCH), 256, 0, stream>>>(qkvb, attb);

    gemm_bt<false><<<dim3(EMB / 128, MROWS / 128), 256, 0, stream>>>(
        attb, wot, b_out, d_out, MROWS, EMB, EMB);
}

// Round 7
// 283.344 us; speedup vs baseline: 1.1299x; 1.1299x over previous
//
#include <hip/hip_runtime.h>
#include <math.h>

#define BATCH 2
#define SEQ   2048
#define EMB   1024
#define HEADS 16
#define N3E   3072
#define MROWS (BATCH*SEQ)     // 4096

typedef __attribute__((ext_vector_type(8))) short  bf16x8;
typedef __attribute__((ext_vector_type(4))) float  f32x4;

__device__ __forceinline__ ushort f2bu(float f) {
    // fp32 -> bf16 bits, round-to-nearest-even (inputs are finite; no NaN path)
    union { float f; unsigned u; } x; x.f = f;
    unsigned r = x.u + 0x7FFFu + ((x.u >> 16) & 1u);
    return (ushort)(r >> 16);
}

// ---------------------------------------------------------------------------
// float -> bf16 cast, 4 elements/thread
// ---------------------------------------------------------------------------
__global__ void cast_bf16(const float* __restrict__ in, ushort* __restrict__ out, int n4) {
    int i = blockIdx.x * blockDim.x + threadIdx.x;
    if (i < n4) {
        float4 v = ((const float4*)in)[i];
        ushort4 o;
        o.x = f2bu(v.x); o.y = f2bu(v.y); o.z = f2bu(v.z); o.w = f2bu(v.w);
        ((ushort4*)out)[i] = o;
    }
}

// ---------------------------------------------------------------------------
// W[K][N] fp32 -> Wt[N][K] bf16 (32x32 tiles via LDS)
// ---------------------------------------------------------------------------
__global__ void transpose_cast(const float* __restrict__ W, ushort* __restrict__ Wt,
                               int K, int N) {
    __shared__ float t[32][33];
    const int bn = blockIdx.x * 32, bk = blockIdx.y * 32;
    const int tx = threadIdx.x, ty = threadIdx.y;   // (32, 8)
    #pragma unroll
    for (int j = 0; j < 4; ++j)
        t[ty + j * 8][tx] = W[(size_t)(bk + ty + j * 8) * N + bn + tx];
    __syncthreads();
    #pragma unroll
    for (int j = 0; j < 4; ++j)
        Wt[(size_t)(bn + ty + j * 8) * K + bk + tx] = f2bu(t[tx][ty + j * 8]);
}

// ---------------------------------------------------------------------------
// V transpose: qkv (reference reshape view) -> VtG[bh][d][l], bf16.
// v[b,h,l,d] = qkv[(b*2048 + h*128 + (l>>4))*3072 + (l&15)*192 + 128 + d]
// 32(l) x 32(d) tiles via LDS, +1-ushort pad => conflict-free column reads.
// ---------------------------------------------------------------------------
__global__ void transpose_v(const ushort* __restrict__ qkv, ushort* __restrict__ VtG) {
    __shared__ ushort t[32][33];
    const int l0 = blockIdx.x * 32, d0 = blockIdx.y * 32, bh = blockIdx.z;
    const int rowbase = (bh >> 4) * SEQ + (bh & 15) * 128;
    const int tx = threadIdx.x, ty = threadIdx.y;   // (32, 8)
    #pragma unroll
    for (int j = 0; j < 4; ++j) {
        const int l = l0 + ty + j * 8;
        t[ty + j * 8][tx] = qkv[(size_t)(rowbase + (l >> 4)) * N3E
                                + (l & 15) * 192 + 128 + d0 + tx];
    }
    __syncthreads();
    #pragma unroll
    for (int j = 0; j < 4; ++j)
        VtG[((size_t)bh * 64 + d0 + ty + j * 8) * SEQ + l0 + tx] = t[tx][ty + j * 8];
}

// ---------------------------------------------------------------------------
// MFMA GEMM: C[M][N] = A[M][K](bf16) * Bt[N][K]^T(bf16) + bias, out fp32 or bf16.
// 128x128 tile, BK=32, 4 waves (2x2), each wave 64x64 = 4x4 fragments 16x16x32.
// ---------------------------------------------------------------------------
template<bool OUT_BF16>
__global__ __launch_bounds__(256) void gemm_bt(const ushort* __restrict__ A,
                                               const ushort* __restrict__ Bt,
                                               const float* __restrict__ bias,
                                               void* __restrict__ Cout,
                                               int M, int N, int K)
{
    __shared__ ushort As[128][40];   // rows 80B (16B-mult), 2-way read conflicts
    __shared__ ushort Bs[128][40];

    const int tid  = threadIdx.x;
    const int lane = tid & 63, w = tid >> 6;
    const int wr = w >> 1, wc = w & 1;
    const int l15 = lane & 15, l4 = lane >> 4;
    const int m0 = blockIdx.y * 128, n0 = blockIdx.x * 128;

    const f32x4 fzero = {0.f, 0.f, 0.f, 0.f};
    f32x4 acc[4][4];
    #pragma unroll
    for (int m = 0; m < 4; ++m)
        #pragma unroll
        for (int n = 0; n < 4; ++n) acc[m][n] = fzero;

    for (int k0 = 0; k0 < K; k0 += 32) {
        #pragma unroll
        for (int r = 0; r < 2; ++r) {
            const int i2 = tid + r * 256;         // 512 x 16B covers both tiles' halves
            const int row = i2 >> 2, seg = i2 & 3;
            *(bf16x8*)&As[row][seg * 8] =
                *(const bf16x8*)&A[(size_t)(m0 + row) * K + k0 + seg * 8];
            *(bf16x8*)&Bs[row][seg * 8] =
                *(const bf16x8*)&Bt[(size_t)(n0 + row) * K + k0 + seg * 8];
        }
        __syncthreads();

        bf16x8 am[4], bn[4];
        #pragma unroll
        for (int m = 0; m < 4; ++m) am[m] = *(bf16x8*)&As[wr * 64 + m * 16 + l15][l4 * 8];
        #pragma unroll
        for (int n = 0; n < 4; ++n) bn[n] = *(bf16x8*)&Bs[wc * 64 + n * 16 + l15][l4 * 8];
        #pragma unroll
        for (int m = 0; m < 4; ++m)
            #pragma unroll
            for (int n = 0; n < 4; ++n)
                acc[m][n] = __builtin_amdgcn_mfma_f32_16x16x32_bf16(am[m], bn[n], acc[m][n], 0, 0, 0);
        __syncthreads();
    }

    // Epilogue. C/D layout (HW-verified): row=(lane>>4)*4+reg, col=lane&15.
    #pragma unroll
    for (int m = 0; m < 4; ++m)
        #pragma unroll
        for (int n = 0; n < 4; ++n)
            #pragma unroll
            for (int r = 0; r < 4; ++r) {
                const int row = m0 + wr * 64 + m * 16 + l4 * 4 + r;
                const int col = n0 + wc * 64 + n * 16 + l15;
                const float v = acc[m][n][r] + bias[col];
                if (OUT_BF16) ((ushort*)Cout)[(size_t)row * N + col] = f2bu(v);
                else          ((float*)Cout)[(size_t)row * N + col]  = v;
            }
}

// ---------------------------------------------------------------------------
// Flash attention, bf16 MFMA. Block = (qtile 64, h, b), 4 waves; wave w owns
// q rows qt*64 + w*16 .. +15. KV tiles of 64. Online softmax in fp32.
// K staged from qkv view; V staged from pre-transposed VtG[bh][d][l] with
// conflict-free row copies (was: 16-way-conflicted LDS scatter).
// ---------------------------------------------------------------------------
__global__ __launch_bounds__(256) void mha_mfma(const ushort* __restrict__ qkv,
                                                const ushort* __restrict__ VtG,
                                                ushort* __restrict__ att)
{
    __shared__ ushort Ks [64][72];     // [kv][d]   rows 144B
    __shared__ ushort Vts[64][72];     // [d][kv]
    __shared__ ushort Ps [4][16][72];  // per-wave P [q][kv]

    const int tid  = threadIdx.x;
    const int lane = tid & 63, w = tid >> 6;
    const int l15 = lane & 15, l4 = lane >> 4;
    const int qt = blockIdx.x, h = blockIdx.y, b = blockIdx.z;
    const size_t rowbase = (size_t)b * SEQ + (size_t)h * 128;
    const size_t vbase   = ((size_t)(b * 16 + h)) * 64 * SEQ;

    // Q fragments (held in registers for all 32 KV tiles)
    bf16x8 aq[2];
    {
        const int lq = qt * 64 + w * 16 + l15;
        const size_t base = (rowbase + (lq >> 4)) * N3E + (size_t)(lq & 15) * 192;
        aq[0] = *(const bf16x8*)&qkv[base +      l4 * 8];
        aq[1] = *(const bf16x8*)&qkv[base + 32 + l4 * 8];
    }

    const f32x4 fzero = {0.f, 0.f, 0.f, 0.f};
    float m_run[4] = {-INFINITY, -INFINITY, -INFINITY, -INFINITY};
    float l_run[4] = {0.f, 0.f, 0.f, 0.f};
    f32x4 o[4];
    #pragma unroll
    for (int f = 0; f < 4; ++f) o[f] = fzero;

    for (int jt = 0; jt < 32; ++jt) {
        __syncthreads();   // Ks/Vts/Ps free (prev PV done)

        // Stage K rows (qkv view) and V rows (VtG, already [d][l]).
        #pragma unroll
        for (int r = 0; r < 2; ++r) {
            const int i2 = tid + r * 256;
            const int row = i2 >> 3, seg = i2 & 7;      // row: kv for K, d for V
            const int kv = jt * 64 + row;
            const size_t gb = (rowbase + (kv >> 4)) * N3E + (size_t)(kv & 15) * 192;
            *(bf16x8*)&Ks[row][seg * 8]  = *(const bf16x8*)&qkv[gb + 64 + seg * 8];
            *(bf16x8*)&Vts[row][seg * 8] =
                *(const bf16x8*)&VtG[vbase + (size_t)row * SEQ + jt * 64 + seg * 8];
        }
        __syncthreads();

        // S = Q K^T (A=Q rows, B-frag = K rows read as columns of K^T)
        f32x4 s4[4];
        #pragma unroll
        for (int f = 0; f < 4; ++f) s4[f] = fzero;
        #pragma unroll
        for (int s = 0; s < 2; ++s)
            #pragma unroll
            for (int f = 0; f < 4; ++f) {
                const bf16x8 kb = *(bf16x8*)&Ks[f * 16 + l15][s * 32 + l4 * 8];
                s4[f] = __builtin_amdgcn_mfma_f32_16x16x32_bf16(aq[s], kb, s4[f], 0, 0, 0);
            }
        #pragma unroll
        for (int f = 0; f < 4; ++f) s4[f] *= 0.125f;   // 1/sqrt(64), before max

        // Online softmax. Lane holds rows (l4*4+r), cols f*16+l15.
        #pragma unroll
        for (int r = 0; r < 4; ++r) {
            float rm = fmaxf(fmaxf(s4[0][r], s4[1][r]), fmaxf(s4[2][r], s4[3][r]));
            rm = fmaxf(rm, __shfl_xor(rm, 1, 16));
            rm = fmaxf(rm, __shfl_xor(rm, 2, 16));
            rm = fmaxf(rm, __shfl_xor(rm, 4, 16));
            rm = fmaxf(rm, __shfl_xor(rm, 8, 16));
            const float mn   = fmaxf(m_run[r], rm);
            const float corr = __expf(m_run[r] - mn);   // 0 on first tile
            float p0 = __expf(s4[0][r] - mn);
            float p1 = __expf(s4[1][r] - mn);
            float p2 = __expf(s4[2][r] - mn);
            float p3 = __expf(s4[3][r] - mn);
            float rs = p0 + p1 + p2 + p3;
            rs += __shfl_xor(rs, 1, 16);
            rs += __shfl_xor(rs, 2, 16);
            rs += __shfl_xor(rs, 4, 16);
            rs += __shfl_xor(rs, 8, 16);
            l_run[r] = l_run[r] * corr + rs;
            m_run[r] = mn;
            #pragma unroll
            for (int f = 0; f < 4; ++f) o[f][r] *= corr;
            const int qrow = l4 * 4 + r;
            Ps[w][qrow][0 * 16 + l15] = f2bu(p0);
            Ps[w][qrow][1 * 16 + l15] = f2bu(p1);
            Ps[w][qrow][2 * 16 + l15] = f2bu(p2);
            Ps[w][qrow][3 * 16 + l15] = f2bu(p3);
        }
        __syncthreads();   // Ps complete (also orders LDS within wave)

        // O += P V  (A=P rows q=l&15; B-frag = Vts rows = V columns)
        #pragma unroll
        for (int s = 0; s < 2; ++s) {
            const bf16x8 pa = *(bf16x8*)&Ps[w][l15][s * 32 + l4 * 8];
            #pragma unroll
            for (int f = 0; f < 4; ++f) {
                const bf16x8 vb = *(bf16x8*)&Vts[f * 16 + l15][s * 32 + l4 * 8];
                o[f] = __builtin_amdgcn_mfma_f32_16x16x32_bf16(pa, vb, o[f], 0, 0, 0);
            }
        }
    }

    // Epilogue: normalize, write att[b*2048+l][h*64+d] as bf16.
    #pragma unroll
    for (int r = 0; r < 4; ++r) {
        const float inv = 1.f / l_run[r];
        const int lq = qt * 64 + w * 16 + l4 * 4 + r;
        const size_t orow = ((size_t)b * SEQ + lq) * EMB + h * 64;
        #pragma unroll
        for (int f = 0; f < 4; ++f)
            att[orow + f * 16 + l15] = f2bu(o[f][r] * inv);
    }
}

// ---------------------------------------------------------------------------
extern "C" void kernel_launch(void* const* d_in, const int* in_sizes, int n_in,
                              void* d_out, int out_size, void* d_ws, size_t ws_size,
                              hipStream_t stream)
{
    const float* x     = (const float*)d_in[0];
    const float* W_qkv = (const float*)d_in[1];
    const float* b_qkv = (const float*)d_in[2];
    const float* W_out = (const float*)d_in[3];
    const float* b_out = (const float*)d_in[4];

    ushort* xb   = (ushort*)d_ws;                        // 4096x1024  (8 MB)
    ushort* wqt  = xb   + (size_t)MROWS * EMB;           // 3072x1024  (6 MB)
    ushort* wot  = wqt  + (size_t)N3E * EMB;             // 1024x1024  (2 MB)
    ushort* qkvb = wot  + (size_t)EMB * EMB;             // 4096x3072  (24 MB)
    ushort* attb = qkvb + (size_t)MROWS * N3E;           // 4096x1024  (8 MB)
    ushort* vtg  = xb;   // reuse: xb is dead after the QKV GEMM (8 MB needed)

    cast_bf16<<<(MROWS * EMB / 4 + 255) / 256, 256, 0, stream>>>(x, xb, MROWS * EMB / 4);
    transpose_cast<<<dim3(N3E / 32, EMB / 32), dim3(32, 8), 0, stream>>>(W_qkv, wqt, EMB, N3E);
    transpose_cast<<<dim3(EMB / 32, EMB / 32), dim3(32, 8), 0, stream>>>(W_out, wot, EMB, EMB);

    gemm_bt<true><<<dim3(N3E / 128, MROWS / 128), 256, 0, stream>>>(
        xb, wqt, b_qkv, qkvb, MROWS, N3E, EMB);

    // qkv -> VtG[bh][d][l]  (xb region reused; safe: gemm_bt<true> consumed xb)
    transpose_v<<<dim3(SEQ / 32, 64 / 32, BATCH * HEADS), dim3(32, 8), 0, stream>>>(qkvb, vtg);

    mha_mfma<<<dim3(SEQ / 64, HEADS, BATCH), 256, 0, stream>>>(qkvb, vtg, attb);

    gemm_bt<false><<<dim3(EMB / 128, MROWS / 128), 256, 0, stream>>>(
        attb, wot, b_out, d_out, MROWS, EMB, EMB);
}

// Round 9
// 233.908 us; speedup vs baseline: 1.3687x; 1.2113x over previous
//
#include <hip/hip_runtime.h>
#include <math.h>

#define BATCH 2
#define SEQ   2048
#define EMB   1024
#define HEADS 16
#define N3E   3072
#define MROWS (BATCH*SEQ)     // 4096

typedef __attribute__((ext_vector_type(8))) short  bf16x8;
typedef __attribute__((ext_vector_type(4))) float  f32x4;

__device__ __forceinline__ ushort f2bu(float f) {
    // fp32 -> bf16 bits, round-to-nearest-even (inputs are finite; no NaN path)
    union { float f; unsigned u; } x; x.f = f;
    unsigned r = x.u + 0x7FFFu + ((x.u >> 16) & 1u);
    return (ushort)(r >> 16);
}

// pack two fp32 -> bf16x2 (RNE), single HW instruction
__device__ __forceinline__ unsigned cvtpk_bf16(float lo, float hi) {
    unsigned r;
    asm("v_cvt_pk_bf16_f32 %0, %1, %2" : "=v"(r) : "v"(lo), "v"(hi));
    return r;
}

__device__ __forceinline__ float fexp2(float x) {
#if __has_builtin(__builtin_amdgcn_exp2f)
    return __builtin_amdgcn_exp2f(x);
#else
    return exp2f(x);
#endif
}

// ---------------------------------------------------------------------------
// float -> bf16 cast, 4 elements/thread
// ---------------------------------------------------------------------------
__global__ void cast_bf16(const float* __restrict__ in, ushort* __restrict__ out, int n4) {
    int i = blockIdx.x * blockDim.x + threadIdx.x;
    if (i < n4) {
        float4 v = ((const float4*)in)[i];
        ushort4 o;
        o.x = f2bu(v.x); o.y = f2bu(v.y); o.z = f2bu(v.z); o.w = f2bu(v.w);
        ((ushort4*)out)[i] = o;
    }
}

// ---------------------------------------------------------------------------
// W[K][N] fp32 -> Wt[N][K] bf16 (32x32 tiles via LDS)
// ---------------------------------------------------------------------------
__global__ void transpose_cast(const float* __restrict__ W, ushort* __restrict__ Wt,
                               int K, int N) {
    __shared__ float t[32][33];
    const int bn = blockIdx.x * 32, bk = blockIdx.y * 32;
    const int tx = threadIdx.x, ty = threadIdx.y;   // (32, 8)
    #pragma unroll
    for (int j = 0; j < 4; ++j)
        t[ty + j * 8][tx] = W[(size_t)(bk + ty + j * 8) * N + bn + tx];
    __syncthreads();
    #pragma unroll
    for (int j = 0; j < 4; ++j)
        Wt[(size_t)(bn + ty + j * 8) * K + bk + tx] = f2bu(t[tx][ty + j * 8]);
}

// ---------------------------------------------------------------------------
// V transpose: qkv (reference reshape view) -> VtG[bh][d][l], bf16.
// v[b,h,l,d] = qkv[(b*2048 + h*128 + (l>>4))*3072 + (l&15)*192 + 128 + d]
// ---------------------------------------------------------------------------
__global__ void transpose_v(const ushort* __restrict__ qkv, ushort* __restrict__ VtG) {
    __shared__ ushort t[32][33];
    const int l0 = blockIdx.x * 32, d0 = blockIdx.y * 32, bh = blockIdx.z;
    const int rowbase = (bh >> 4) * SEQ + (bh & 15) * 128;
    const int tx = threadIdx.x, ty = threadIdx.y;   // (32, 8)
    #pragma unroll
    for (int j = 0; j < 4; ++j) {
        const int l = l0 + ty + j * 8;
        t[ty + j * 8][tx] = qkv[(size_t)(rowbase + (l >> 4)) * N3E
                                + (l & 15) * 192 + 128 + d0 + tx];
    }
    __syncthreads();
    #pragma unroll
    for (int j = 0; j < 4; ++j)
        VtG[((size_t)bh * 64 + d0 + ty + j * 8) * SEQ + l0 + tx] = t[tx][ty + j * 8];
}

// ---------------------------------------------------------------------------
// MFMA GEMM: C[M][N] = A[M][K](bf16) * Bt[N][K]^T(bf16) + bias, out fp32 or bf16.
// 128x128 tile, BK=32, 4 waves (2x2), each wave 64x64 = 4x4 fragments 16x16x32.
// ---------------------------------------------------------------------------
template<bool OUT_BF16>
__global__ __launch_bounds__(256) void gemm_bt(const ushort* __restrict__ A,
                                               const ushort* __restrict__ Bt,
                                               const float* __restrict__ bias,
                                               void* __restrict__ Cout,
                                               int M, int N, int K)
{
    __shared__ ushort As[128][40];   // rows 80B (16B-mult), 2-way read conflicts
    __shared__ ushort Bs[128][40];

    const int tid  = threadIdx.x;
    const int lane = tid & 63, w = tid >> 6;
    const int wr = w >> 1, wc = w & 1;
    const int l15 = lane & 15, l4 = lane >> 4;
    const int m0 = blockIdx.y * 128, n0 = blockIdx.x * 128;

    const f32x4 fzero = {0.f, 0.f, 0.f, 0.f};
    f32x4 acc[4][4];
    #pragma unroll
    for (int m = 0; m < 4; ++m)
        #pragma unroll
        for (int n = 0; n < 4; ++n) acc[m][n] = fzero;

    for (int k0 = 0; k0 < K; k0 += 32) {
        #pragma unroll
        for (int r = 0; r < 2; ++r) {
            const int i2 = tid + r * 256;         // 512 x 16B covers both tiles' halves
            const int row = i2 >> 2, seg = i2 & 3;
            *(bf16x8*)&As[row][seg * 8] =
                *(const bf16x8*)&A[(size_t)(m0 + row) * K + k0 + seg * 8];
            *(bf16x8*)&Bs[row][seg * 8] =
                *(const bf16x8*)&Bt[(size_t)(n0 + row) * K + k0 + seg * 8];
        }
        __syncthreads();

        bf16x8 am[4], bn[4];
        #pragma unroll
        for (int m = 0; m < 4; ++m) am[m] = *(bf16x8*)&As[wr * 64 + m * 16 + l15][l4 * 8];
        #pragma unroll
        for (int n = 0; n < 4; ++n) bn[n] = *(bf16x8*)&Bs[wc * 64 + n * 16 + l15][l4 * 8];
        #pragma unroll
        for (int m = 0; m < 4; ++m)
            #pragma unroll
            for (int n = 0; n < 4; ++n)
                acc[m][n] = __builtin_amdgcn_mfma_f32_16x16x32_bf16(am[m], bn[n], acc[m][n], 0, 0, 0);
        __syncthreads();
    }

    // Epilogue. C/D layout (HW-verified): row=(lane>>4)*4+reg, col=lane&15.
    #pragma unroll
    for (int m = 0; m < 4; ++m)
        #pragma unroll
        for (int n = 0; n < 4; ++n)
            #pragma unroll
            for (int r = 0; r < 4; ++r) {
                const int row = m0 + wr * 64 + m * 16 + l4 * 4 + r;
                const int col = n0 + wc * 64 + n * 16 + l15;
                const float v = acc[m][n][r] + bias[col];
                if (OUT_BF16) ((ushort*)Cout)[(size_t)row * N + col] = f2bu(v);
                else          ((float*)Cout)[(size_t)row * N + col]  = v;
            }
}

// ---------------------------------------------------------------------------
// Flash attention, bf16 MFMA, SWAPPED operands (S^T = K·Q^T, O^T = V^T·P^T).
// Block = (qtile 64, h, b), 4 waves; wave w owns q rows qt*64+w*16 .. +15.
// Lane (l4,l15) holds S[kv=f*16+l4*4+r][q=w*16+l15]: softmax row is lane-local
// (15 in-reg fmax + 2 shfl, vs 32 shfl before). m/l scalar per lane. P packed
// via v_cvt_pk_bf16_f32 into wave-private Ps (no barrier). exp2-domain with
// defer-rescale (THR=8 nats): exact softmax, rescale mostly skipped.
// ---------------------------------------------------------------------------
__global__ __launch_bounds__(256) void mha_mfma(const ushort* __restrict__ qkv,
                                                const ushort* __restrict__ VtG,
                                                ushort* __restrict__ att)
{
    __shared__ ushort Ks [64][72];     // [kv][d]   rows 144B
    __shared__ ushort Vts[64][72];     // [d][kv]
    __shared__ ushort Ps [4][16][72];  // per-wave P [q][kv]

    const int tid  = threadIdx.x;
    const int lane = tid & 63, w = tid >> 6;
    const int l15 = lane & 15, l4 = lane >> 4;
    const int qt = blockIdx.x, h = blockIdx.y, b = blockIdx.z;
    const size_t rowbase = (size_t)b * SEQ + (size_t)h * 128;
    const size_t vbase   = ((size_t)(b * 16 + h)) * 64 * SEQ;

    // Q B-fragment: B[k=d][col=q=l15], k = l4*8+j (+32 for aq[1])
    bf16x8 aq[2];
    {
        const int lq = qt * 64 + w * 16 + l15;
        const size_t base = (rowbase + (lq >> 4)) * N3E + (size_t)(lq & 15) * 192;
        aq[0] = *(const bf16x8*)&qkv[base +      l4 * 8];
        aq[1] = *(const bf16x8*)&qkv[base + 32 + l4 * 8];
    }

    const f32x4 fzero = {0.f, 0.f, 0.f, 0.f};
    float m_run = -INFINITY, l_run = 0.f;
    f32x4 o[4];
    #pragma unroll
    for (int f = 0; f < 4; ++f) o[f] = fzero;

    const float SC = 0.125f * 1.4426950408889634f;   // (1/sqrt(64)) * log2(e)

    for (int jt = 0; jt < 32; ++jt) {
        __syncthreads();   // prev tile's K/V reads done -> safe to restage

        #pragma unroll
        for (int r = 0; r < 2; ++r) {
            const int i2 = tid + r * 256;
            const int row = i2 >> 3, seg = i2 & 7;      // row: kv for K, d for V
            const int kv = jt * 64 + row;
            const size_t gb = (rowbase + (kv >> 4)) * N3E + (size_t)(kv & 15) * 192;
            *(bf16x8*)&Ks[row][seg * 8]  = *(const bf16x8*)&qkv[gb + 64 + seg * 8];
            *(bf16x8*)&Vts[row][seg * 8] =
                *(const bf16x8*)&VtG[vbase + (size_t)row * SEQ + jt * 64 + seg * 8];
        }
        __syncthreads();

        // S^T = K·Q^T: A = K rows (kv), B = Q. Lane: S[kv=f*16+l4*4+r][q=l15].
        f32x4 s4[4];
        #pragma unroll
        for (int f = 0; f < 4; ++f) s4[f] = fzero;
        #pragma unroll
        for (int s = 0; s < 2; ++s)
            #pragma unroll
            for (int f = 0; f < 4; ++f) {
                const bf16x8 kb = *(bf16x8*)&Ks[f * 16 + l15][s * 32 + l4 * 8];
                s4[f] = __builtin_amdgcn_mfma_f32_16x16x32_bf16(kb, aq[s], s4[f], 0, 0, 0);
            }
        #pragma unroll
        for (int f = 0; f < 4; ++f) s4[f] *= SC;       // log2 domain

        // Row max: 16 in-register + quad (lanes l15, +16, +32, +48)
        float pmax;
        {
            float a0 = fmaxf(fmaxf(s4[0][0], s4[0][1]), fmaxf(s4[0][2], s4[0][3]));
            float a1 = fmaxf(fmaxf(s4[1][0], s4[1][1]), fmaxf(s4[1][2], s4[1][3]));
            float a2 = fmaxf(fmaxf(s4[2][0], s4[2][1]), fmaxf(s4[2][2], s4[2][3]));
            float a3 = fmaxf(fmaxf(s4[3][0], s4[3][1]), fmaxf(s4[3][2], s4[3][3]));
            pmax = fmaxf(fmaxf(a0, a1), fmaxf(a2, a3));
            pmax = fmaxf(pmax, __shfl_xor(pmax, 16));
            pmax = fmaxf(pmax, __shfl_xor(pmax, 32));
        }

        // Defer-rescale: skip O/l rescale unless max grew past THR (11.5 log2
        // ~ 8 nats). Exact: o and l always carry the same scale.
        if (!__all(pmax - m_run <= 11.5f)) {
            const float mn   = fmaxf(m_run, pmax);
            const float corr = fexp2(m_run - mn);      // 0 on first tile
            #pragma unroll
            for (int f = 0; f < 4; ++f) o[f] *= corr;
            l_run *= corr;
            m_run = mn;
        }

        // P = 2^(s - m), row sum (15 in-reg adds + 2 shfl)
        float rs = 0.f;
        #pragma unroll
        for (int f = 0; f < 4; ++f)
            #pragma unroll
            for (int r = 0; r < 4; ++r) {
                s4[f][r] = fexp2(s4[f][r] - m_run);
                rs += s4[f][r];
            }
        rs += __shfl_xor(rs, 16);
        rs += __shfl_xor(rs, 32);
        l_run += rs;

        // Pack P -> bf16 pairs, store to wave-private Ps[q=l15][kv] (no barrier)
        #pragma unroll
        for (int f = 0; f < 4; ++f) {
            const unsigned lo = cvtpk_bf16(s4[f][0], s4[f][1]);
            const unsigned hi = cvtpk_bf16(s4[f][2], s4[f][3]);
            *(unsigned*)&Ps[w][l15][f * 16 + l4 * 4]     = lo;
            *(unsigned*)&Ps[w][l15][f * 16 + l4 * 4 + 2] = hi;
        }

        // O^T += V^T·P^T: A = Vts rows (d), B = P. Lane: O[d=f*16+l4*4+r][q=l15].
        #pragma unroll
        for (int s = 0; s < 2; ++s) {
            const bf16x8 pb = *(bf16x8*)&Ps[w][l15][s * 32 + l4 * 8];
            #pragma unroll
            for (int f = 0; f < 4; ++f) {
                const bf16x8 vb = *(bf16x8*)&Vts[f * 16 + l15][s * 32 + l4 * 8];
                o[f] = __builtin_amdgcn_mfma_f32_16x16x32_bf16(vb, pb, o[f], 0, 0, 0);
            }
        }
    }

    // Epilogue: normalize, write att[b*2048 + q][h*64 + d], d contiguous x4.
    const float inv = 1.f / l_run;
    const int lqo = qt * 64 + w * 16 + l15;
    const size_t obase = ((size_t)b * SEQ + lqo) * EMB + h * 64;
    #pragma unroll
    for (int f = 0; f < 4; ++f) {
        uint2 pk;
        pk.x = cvtpk_bf16(o[f][0] * inv, o[f][1] * inv);
        pk.y = cvtpk_bf16(o[f][2] * inv, o[f][3] * inv);
        *(uint2*)&att[obase + f * 16 + l4 * 4] = pk;
    }
}

// ---------------------------------------------------------------------------
extern "C" void kernel_launch(void* const* d_in, const int* in_sizes, int n_in,
                              void* d_out, int out_size, void* d_ws, size_t ws_size,
                              hipStream_t stream)
{
    const float* x     = (const float*)d_in[0];
    const float* W_qkv = (const float*)d_in[1];
    const float* b_qkv = (const float*)d_in[2];
    const float* W_out = (const float*)d_in[3];
    const float* b_out = (const float*)d_in[4];

    ushort* xb   = (ushort*)d_ws;                        // 4096x1024  (8 MB)
    ushort* wqt  = xb   + (size_t)MROWS * EMB;           // 3072x1024  (6 MB)
    ushort* wot  = wqt  + (size_t)N3E * EMB;             // 1024x1024  (2 MB)
    ushort* qkvb = wot  + (size_t)EMB * EMB;             // 4096x3072  (24 MB)
    ushort* attb = qkvb + (size_t)MROWS * N3E;           // 4096x1024  (8 MB)
    ushort* vtg  = xb;   // reuse: xb is dead after the QKV GEMM (8 MB needed)

    cast_bf16<<<(MROWS * EMB / 4 + 255) / 256, 256, 0, stream>>>(x, xb, MROWS * EMB / 4);
    transpose_cast<<<dim3(N3E / 32, EMB / 32), dim3(32, 8), 0, stream>>>(W_qkv, wqt, EMB, N3E);
    transpose_cast<<<dim3(EMB / 32, EMB / 32), dim3(32, 8), 0, stream>>>(W_out, wot, EMB, EMB);

    gemm_bt<true><<<dim3(N3E / 128, MROWS / 128), 256, 0, stream>>>(
        xb, wqt, b_qkv, qkvb, MROWS, N3E, EMB);

    // qkv -> VtG[bh][d][l]  (xb region reused; safe: gemm_bt<true> consumed xb)
    transpose_v<<<dim3(SEQ / 32, 64 / 32, BATCH * HEADS), dim3(32, 8), 0, stream>>>(qkvb, vtg);

    mha_mfma<<<dim3(SEQ / 64, HEADS, BATCH), 256, 0, stream>>>(qkvb, vtg, attb);

    gemm_bt<false><<<dim3(EMB / 128, MROWS / 128), 256, 0, stream>>>(
        attb, wot, b_out, d_out, MROWS, EMB, EMB);
}

// Round 10
// 230.758 us; speedup vs baseline: 1.3874x; 1.0137x over previous
//
#include <hip/hip_runtime.h>
#include <math.h>

#define BATCH 2
#define SEQ   2048
#define EMB   1024
#define HEADS 16
#define N3E   3072
#define MROWS (BATCH*SEQ)     // 4096

typedef __attribute__((ext_vector_type(8))) short  bf16x8;
typedef __attribute__((ext_vector_type(4))) float  f32x4;

typedef __attribute__((address_space(1))) unsigned int gu32;   // global
typedef __attribute__((address_space(3))) unsigned int lu32;   // LDS

__device__ __forceinline__ ushort f2bu(float f) {
    // fp32 -> bf16 bits, round-to-nearest-even (inputs are finite; no NaN path)
    union { float f; unsigned u; } x; x.f = f;
    unsigned r = x.u + 0x7FFFu + ((x.u >> 16) & 1u);
    return (ushort)(r >> 16);
}

// pack two fp32 -> bf16x2 (RNE), single HW instruction
__device__ __forceinline__ unsigned cvtpk_bf16(float lo, float hi) {
    unsigned r;
    asm("v_cvt_pk_bf16_f32 %0, %1, %2" : "=v"(r) : "v"(lo), "v"(hi));
    return r;
}

__device__ __forceinline__ float fexp2(float x) {
#if __has_builtin(__builtin_amdgcn_exp2f)
    return __builtin_amdgcn_exp2f(x);
#else
    return exp2f(x);
#endif
}

// ---------------------------------------------------------------------------
// float -> bf16 cast, 4 elements/thread
// ---------------------------------------------------------------------------
__global__ void cast_bf16(const float* __restrict__ in, ushort* __restrict__ out, int n4) {
    int i = blockIdx.x * blockDim.x + threadIdx.x;
    if (i < n4) {
        float4 v = ((const float4*)in)[i];
        ushort4 o;
        o.x = f2bu(v.x); o.y = f2bu(v.y); o.z = f2bu(v.z); o.w = f2bu(v.w);
        ((ushort4*)out)[i] = o;
    }
}

// ---------------------------------------------------------------------------
// W[K][N] fp32 -> Wt[N][K] bf16 (32x32 tiles via LDS)
// ---------------------------------------------------------------------------
__global__ void transpose_cast(const float* __restrict__ W, ushort* __restrict__ Wt,
                               int K, int N) {
    __shared__ float t[32][33];
    const int bn = blockIdx.x * 32, bk = blockIdx.y * 32;
    const int tx = threadIdx.x, ty = threadIdx.y;   // (32, 8)
    #pragma unroll
    for (int j = 0; j < 4; ++j)
        t[ty + j * 8][tx] = W[(size_t)(bk + ty + j * 8) * N + bn + tx];
    __syncthreads();
    #pragma unroll
    for (int j = 0; j < 4; ++j)
        Wt[(size_t)(bn + ty + j * 8) * K + bk + tx] = f2bu(t[tx][ty + j * 8]);
}

// ---------------------------------------------------------------------------
// V transpose: qkv (reference reshape view) -> VtG[bh][d][l], bf16.
// v[b,h,l,d] = qkv[(b*2048 + h*128 + (l>>4))*3072 + (l&15)*192 + 128 + d]
// ---------------------------------------------------------------------------
__global__ void transpose_v(const ushort* __restrict__ qkv, ushort* __restrict__ VtG) {
    __shared__ ushort t[32][33];
    const int l0 = blockIdx.x * 32, d0 = blockIdx.y * 32, bh = blockIdx.z;
    const int rowbase = (bh >> 4) * SEQ + (bh & 15) * 128;
    const int tx = threadIdx.x, ty = threadIdx.y;   // (32, 8)
    #pragma unroll
    for (int j = 0; j < 4; ++j) {
        const int l = l0 + ty + j * 8;
        t[ty + j * 8][tx] = qkv[(size_t)(rowbase + (l >> 4)) * N3E
                                + (l & 15) * 192 + 128 + d0 + tx];
    }
    __syncthreads();
    #pragma unroll
    for (int j = 0; j < 4; ++j)
        VtG[((size_t)bh * 64 + d0 + ty + j * 8) * SEQ + l0 + tx] = t[tx][ty + j * 8];
}

// ---------------------------------------------------------------------------
// MFMA GEMM: C[M][N] = A[M][K](bf16) * Bt[N][K]^T(bf16) + bias, out fp32/bf16.
// 128x128 tile, BK=32, 4 waves (2x2), each wave 64x64 = 4x4 frags 16x16x32.
// Staging via global_load_lds width=16 (m97 pattern): LDS is LINEAR [128][32]
// (64B rows, no pad — HW writes base+lane*16; lane->(row=l>>2, k=(l&3)*8)
// equals lane*16 exactly). __syncthreads drains vmcnt before use.
// ---------------------------------------------------------------------------
template<bool OUT_BF16>
__global__ __launch_bounds__(256) void gemm_bt(const ushort* __restrict__ A,
                                               const ushort* __restrict__ Bt,
                                               const float* __restrict__ bias,
                                               void* __restrict__ Cout,
                                               int M, int N, int K)
{
    __shared__ ushort As[128][32];
    __shared__ ushort Bs[128][32];

    const int tid  = threadIdx.x;
    const int lane = tid & 63, w = tid >> 6;
    const int wr = w >> 1, wc = w & 1;
    const int l15 = lane & 15, l4 = lane >> 4;
    const int m0 = blockIdx.y * 128, n0 = blockIdx.x * 128;

    const int srow = lane >> 2;            // staging: row within 16-row group
    const int scol = (lane & 3) * 8;       // staging: k offset (elements)

    const f32x4 fzero = {0.f, 0.f, 0.f, 0.f};
    f32x4 acc[4][4];
    #pragma unroll
    for (int m = 0; m < 4; ++m)
        #pragma unroll
        for (int n = 0; n < 4; ++n) acc[m][n] = fzero;

    for (int k0 = 0; k0 < K; k0 += 32) {
        __syncthreads();   // prev iteration's LDS reads complete
        #pragma unroll
        for (int i = 0; i < 2; ++i) {
            const int r0 = (w * 2 + i) * 16;   // wave-uniform LDS base row
            __builtin_amdgcn_global_load_lds(
                (const gu32*)&A[(size_t)(m0 + r0 + srow) * K + k0 + scol],
                (lu32*)&As[r0][0], 16, 0, 0);
            __builtin_amdgcn_global_load_lds(
                (const gu32*)&Bt[(size_t)(n0 + r0 + srow) * K + k0 + scol],
                (lu32*)&Bs[r0][0], 16, 0, 0);
        }
        __syncthreads();   // drains vmcnt(0): staged tile visible

        bf16x8 am[4], bn[4];
        #pragma unroll
        for (int m = 0; m < 4; ++m) am[m] = *(bf16x8*)&As[wr * 64 + m * 16 + l15][l4 * 8];
        #pragma unroll
        for (int n = 0; n < 4; ++n) bn[n] = *(bf16x8*)&Bs[wc * 64 + n * 16 + l15][l4 * 8];
        #pragma unroll
        for (int m = 0; m < 4; ++m)
            #pragma unroll
            for (int n = 0; n < 4; ++n)
                acc[m][n] = __builtin_amdgcn_mfma_f32_16x16x32_bf16(am[m], bn[n], acc[m][n], 0, 0, 0);
    }

    // Epilogue. C/D layout (HW-verified): row=(lane>>4)*4+reg, col=lane&15.
    #pragma unroll
    for (int m = 0; m < 4; ++m)
        #pragma unroll
        for (int n = 0; n < 4; ++n)
            #pragma unroll
            for (int r = 0; r < 4; ++r) {
                const int row = m0 + wr * 64 + m * 16 + l4 * 4 + r;
                const int col = n0 + wc * 64 + n * 16 + l15;
                const float v = acc[m][n][r] + bias[col];
                if (OUT_BF16) ((ushort*)Cout)[(size_t)row * N + col] = f2bu(v);
                else          ((float*)Cout)[(size_t)row * N + col]  = v;
            }
}

// ---------------------------------------------------------------------------
// Flash attention, bf16 MFMA, SWAPPED operands (S^T = K·Q^T, O^T = V^T·P^T).
// Block = (qtile 64, h, b), 4 waves; wave w owns q rows qt*64+w*16 .. +15.
// Lane (l4,l15) holds S[kv=f*16+l4*4+r][q=w*16+l15]: softmax row is lane-local
// (15 in-reg fmax + 2 shfl). m/l scalar per lane. P packed via
// v_cvt_pk_bf16_f32 into wave-private Ps (no barrier). exp2-domain with
// defer-rescale (THR~8 nats): exact softmax, rescale mostly skipped.
// ---------------------------------------------------------------------------
__global__ __launch_bounds__(256) void mha_mfma(const ushort* __restrict__ qkv,
                                                const ushort* __restrict__ VtG,
                                                ushort* __restrict__ att)
{
    __shared__ ushort Ks [64][72];     // [kv][d]   rows 144B
    __shared__ ushort Vts[64][72];     // [d][kv]
    __shared__ ushort Ps [4][16][72];  // per-wave P [q][kv]

    const int tid  = threadIdx.x;
    const int lane = tid & 63, w = tid >> 6;
    const int l15 = lane & 15, l4 = lane >> 4;
    const int qt = blockIdx.x, h = blockIdx.y, b = blockIdx.z;
    const size_t rowbase = (size_t)b * SEQ + (size_t)h * 128;
    const size_t vbase   = ((size_t)(b * 16 + h)) * 64 * SEQ;

    // Q B-fragment: B[k=d][col=q=l15], k = l4*8+j (+32 for aq[1])
    bf16x8 aq[2];
    {
        const int lq = qt * 64 + w * 16 + l15;
        const size_t base = (rowbase + (lq >> 4)) * N3E + (size_t)(lq & 15) * 192;
        aq[0] = *(const bf16x8*)&qkv[base +      l4 * 8];
        aq[1] = *(const bf16x8*)&qkv[base + 32 + l4 * 8];
    }

    const f32x4 fzero = {0.f, 0.f, 0.f, 0.f};
    float m_run = -INFINITY, l_run = 0.f;
    f32x4 o[4];
    #pragma unroll
    for (int f = 0; f < 4; ++f) o[f] = fzero;

    const float SC = 0.125f * 1.4426950408889634f;   // (1/sqrt(64)) * log2(e)

    for (int jt = 0; jt < 32; ++jt) {
        __syncthreads();   // prev tile's K/V reads done -> safe to restage

        #pragma unroll
        for (int r = 0; r < 2; ++r) {
            const int i2 = tid + r * 256;
            const int row = i2 >> 3, seg = i2 & 7;      // row: kv for K, d for V
            const int kv = jt * 64 + row;
            const size_t gb = (rowbase + (kv >> 4)) * N3E + (size_t)(kv & 15) * 192;
            *(bf16x8*)&Ks[row][seg * 8]  = *(const bf16x8*)&qkv[gb + 64 + seg * 8];
            *(bf16x8*)&Vts[row][seg * 8] =
                *(const bf16x8*)&VtG[vbase + (size_t)row * SEQ + jt * 64 + seg * 8];
        }
        __syncthreads();

        // S^T = K·Q^T: A = K rows (kv), B = Q. Lane: S[kv=f*16+l4*4+r][q=l15].
        f32x4 s4[4];
        #pragma unroll
        for (int f = 0; f < 4; ++f) s4[f] = fzero;
        #pragma unroll
        for (int s = 0; s < 2; ++s)
            #pragma unroll
            for (int f = 0; f < 4; ++f) {
                const bf16x8 kb = *(bf16x8*)&Ks[f * 16 + l15][s * 32 + l4 * 8];
                s4[f] = __builtin_amdgcn_mfma_f32_16x16x32_bf16(kb, aq[s], s4[f], 0, 0, 0);
            }
        #pragma unroll
        for (int f = 0; f < 4; ++f) s4[f] *= SC;       // log2 domain

        // Row max: 16 in-register + quad (lanes l15, +16, +32, +48)
        float pmax;
        {
            float a0 = fmaxf(fmaxf(s4[0][0], s4[0][1]), fmaxf(s4[0][2], s4[0][3]));
            float a1 = fmaxf(fmaxf(s4[1][0], s4[1][1]), fmaxf(s4[1][2], s4[1][3]));
            float a2 = fmaxf(fmaxf(s4[2][0], s4[2][1]), fmaxf(s4[2][2], s4[2][3]));
            float a3 = fmaxf(fmaxf(s4[3][0], s4[3][1]), fmaxf(s4[3][2], s4[3][3]));
            pmax = fmaxf(fmaxf(a0, a1), fmaxf(a2, a3));
            pmax = fmaxf(pmax, __shfl_xor(pmax, 16));
            pmax = fmaxf(pmax, __shfl_xor(pmax, 32));
        }

        // Defer-rescale: skip O/l rescale unless max grew past THR (11.5 log2
        // ~ 8 nats). Exact: o and l always carry the same scale.
        if (!__all(pmax - m_run <= 11.5f)) {
            const float mn   = fmaxf(m_run, pmax);
            const float corr = fexp2(m_run - mn);      // 0 on first tile
            #pragma unroll
            for (int f = 0; f < 4; ++f) o[f] *= corr;
            l_run *= corr;
            m_run = mn;
        }

        // P = 2^(s - m), row sum (15 in-reg adds + 2 shfl)
        float rs = 0.f;
        #pragma unroll
        for (int f = 0; f < 4; ++f)
            #pragma unroll
            for (int r = 0; r < 4; ++r) {
                s4[f][r] = fexp2(s4[f][r] - m_run);
                rs += s4[f][r];
            }
        rs += __shfl_xor(rs, 16);
        rs += __shfl_xor(rs, 32);
        l_run += rs;

        // Pack P -> bf16 pairs, store to wave-private Ps[q=l15][kv] (no barrier)
        #pragma unroll
        for (int f = 0; f < 4; ++f) {
            const unsigned lo = cvtpk_bf16(s4[f][0], s4[f][1]);
            const unsigned hi = cvtpk_bf16(s4[f][2], s4[f][3]);
            *(unsigned*)&Ps[w][l15][f * 16 + l4 * 4]     = lo;
            *(unsigned*)&Ps[w][l15][f * 16 + l4 * 4 + 2] = hi;
        }

        // O^T += V^T·P^T: A = Vts rows (d), B = P. Lane: O[d=f*16+l4*4+r][q=l15].
        #pragma unroll
        for (int s = 0; s < 2; ++s) {
            const bf16x8 pb = *(bf16x8*)&Ps[w][l15][s * 32 + l4 * 8];
            #pragma unroll
            for (int f = 0; f < 4; ++f) {
                const bf16x8 vb = *(bf16x8*)&Vts[f * 16 + l15][s * 32 + l4 * 8];
                o[f] = __builtin_amdgcn_mfma_f32_16x16x32_bf16(vb, pb, o[f], 0, 0, 0);
            }
        }
    }

    // Epilogue: normalize, write att[b*2048 + q][h*64 + d], d contiguous x4.
    const float inv = 1.f / l_run;
    const int lqo = qt * 64 + w * 16 + l15;
    const size_t obase = ((size_t)b * SEQ + lqo) * EMB + h * 64;
    #pragma unroll
    for (int f = 0; f < 4; ++f) {
        uint2 pk;
        pk.x = cvtpk_bf16(o[f][0] * inv, o[f][1] * inv);
        pk.y = cvtpk_bf16(o[f][2] * inv, o[f][3] * inv);
        *(uint2*)&att[obase + f * 16 + l4 * 4] = pk;
    }
}

// ---------------------------------------------------------------------------
extern "C" void kernel_launch(void* const* d_in, const int* in_sizes, int n_in,
                              void* d_out, int out_size, void* d_ws, size_t ws_size,
                              hipStream_t stream)
{
    const float* x     = (const float*)d_in[0];
    const float* W_qkv = (const float*)d_in[1];
    const float* b_qkv = (const float*)d_in[2];
    const float* W_out = (const float*)d_in[3];
    const float* b_out = (const float*)d_in[4];

    ushort* xb   = (ushort*)d_ws;                        // 4096x1024  (8 MB)
    ushort* wqt  = xb   + (size_t)MROWS * EMB;           // 3072x1024  (6 MB)
    ushort* wot  = wqt  + (size_t)N3E * EMB;             // 1024x1024  (2 MB)
    ushort* qkvb = wot  + (size_t)EMB * EMB;             // 4096x3072  (24 MB)
    ushort* attb = qkvb + (size_t)MROWS * N3E;           // 4096x1024  (8 MB)
    ushort* vtg  = xb;   // reuse: xb is dead after the QKV GEMM (8 MB needed)

    cast_bf16<<<(MROWS * EMB / 4 + 255) / 256, 256, 0, stream>>>(x, xb, MROWS * EMB / 4);
    transpose_cast<<<dim3(N3E / 32, EMB / 32), dim3(32, 8), 0, stream>>>(W_qkv, wqt, EMB, N3E);
    transpose_cast<<<dim3(EMB / 32, EMB / 32), dim3(32, 8), 0, stream>>>(W_out, wot, EMB, EMB);

    gemm_bt<true><<<dim3(N3E / 128, MROWS / 128), 256, 0, stream>>>(
        xb, wqt, b_qkv, qkvb, MROWS, N3E, EMB);

    // qkv -> VtG[bh][d][l]  (xb region reused; safe: gemm_bt<true> consumed xb)
    transpose_v<<<dim3(SEQ / 32, 64 / 32, BATCH * HEADS), dim3(32, 8), 0, stream>>>(qkvb, vtg);

    mha_mfma<<<dim3(SEQ / 64, HEADS, BATCH), 256, 0, stream>>>(qkvb, vtg, attb);

    gemm_bt<false><<<dim3(EMB / 128, MROWS / 128), 256, 0, stream>>>(
        attb, wot, b_out, d_out, MROWS, EMB, EMB);
}